// Round 9
// baseline (580.177 us; speedup 1.0000x reference)
//
#include <hip/hip_runtime.h>

#define T_TOKENS 4096   // B*S
#define DIM      1024   // D
#define NEXP     8      // E
#define FDIM     4096   // F
#define NASSIGN  8192   // T_TOKENS * K
#define PADROWS  8448

typedef __bf16 bf16x8 __attribute__((ext_vector_type(8)));
typedef float  f32x4  __attribute__((ext_vector_type(4)));
typedef short  short4v __attribute__((ext_vector_type(4)));
typedef short  short8v __attribute__((ext_vector_type(8)));
typedef unsigned short us8 __attribute__((ext_vector_type(8)));

__device__ __forceinline__ unsigned short f2b(float f) {
  unsigned u = __builtin_bit_cast(unsigned, f);
  u = u + 0x7fffu + ((u >> 16) & 1u);   // RNE, finite inputs only
  return (unsigned short)(u >> 16);
}
__device__ __forceinline__ float b2f(unsigned short h) {
  unsigned u = ((unsigned)h) << 16;
  return __builtin_bit_cast(float, u);
}
__device__ __forceinline__ void gload_lds16(const void* g, void* l) {
  __builtin_amdgcn_global_load_lds(
      (const __attribute__((address_space(1))) void*)g,
      (__attribute__((address_space(3))) void*)l, 16, 0, 0);
}

// ---------------- router ----------------
__global__ void router_kernel(const float* __restrict__ x, const float* __restrict__ rw,
                              const float* __restrict__ rb, int* __restrict__ tidx,
                              float* __restrict__ tw, int* __restrict__ counts) {
  int gid = blockIdx.x * blockDim.x + threadIdx.x;
  int t = gid >> 6;
  int lane = threadIdx.x & 63;
  if (t >= T_TOKENS) return;
  const float* xr = x + (size_t)t * DIM;
  float acc[NEXP];
#pragma unroll
  for (int e = 0; e < NEXP; ++e) acc[e] = 0.f;
  for (int d = lane; d < DIM; d += 64) {
    float xv = xr[d];
    const float* r = rw + (size_t)d * NEXP;
#pragma unroll
    for (int e = 0; e < NEXP; ++e) acc[e] += xv * r[e];
  }
#pragma unroll
  for (int e = 0; e < NEXP; ++e) {
#pragma unroll
    for (int off = 32; off > 0; off >>= 1) acc[e] += __shfl_xor(acc[e], off);
  }
  if (lane == 0) {
    float lg[NEXP], m = -1e30f;
#pragma unroll
    for (int e = 0; e < NEXP; ++e) { lg[e] = acc[e] + rb[e]; m = fmaxf(m, lg[e]); }
    float p[NEXP], Z = 0.f;
#pragma unroll
    for (int e = 0; e < NEXP; ++e) { p[e] = expf(lg[e] - m); Z += p[e]; }
    int i0 = 0;
#pragma unroll
    for (int e = 1; e < NEXP; ++e) if (p[e] > p[i0]) i0 = e;
    int i1 = (i0 == 0) ? 1 : 0;
#pragma unroll
    for (int e = 0; e < NEXP; ++e) if (e != i0 && p[e] > p[i1]) i1 = e;
    float q0 = p[i0] / Z, q1 = p[i1] / Z;
    float s = q0 + q1 + 1e-8f;
    tidx[t * 2] = i0; tidx[t * 2 + 1] = i1;
    tw[t * 2] = q0 / s; tw[t * 2 + 1] = q1 / s;
    atomicAdd(&counts[i0], 1); atomicAdd(&counts[i1], 1);
  }
}

// ---------------- scan: offsets, cursors, 128-row tile list ----------------
__global__ void scan_kernel(const int* __restrict__ counts, int* __restrict__ offsets,
                            int* __restrict__ cursors, int* __restrict__ ntiles_p,
                            int* __restrict__ tlist) {
  if (threadIdx.x == 0) {
    int s = 0;
    for (int e = 0; e < NEXP; ++e) { offsets[e] = s; cursors[e] = s; s += counts[e]; }
    offsets[NEXP] = s;
    int nt = 0;
    for (int e = 0; e < NEXP; ++e) {
      int ne = counts[e];
      int mts = (ne + 127) >> 7;
      for (int mt = 0; mt < mts; ++mt) tlist[nt++] = (e << 8) | mt;
    }
    *ntiles_p = nt;   // <= 71
  }
}

// ---------------- gather x rows (fp32 -> bf16) ----------------
__global__ void gather_kernel(const float* __restrict__ x, const int* __restrict__ tidx,
                              int* __restrict__ cursors, int* __restrict__ tslot,
                              unsigned short* __restrict__ Xg) {
  int aid = (blockIdx.x * blockDim.x + threadIdx.x) >> 6;
  int lane = threadIdx.x & 63;
  if (aid >= NASSIGN) return;
  int t = aid >> 1, k = aid & 1;
  int e = tidx[t * 2 + k];
  int slot = 0;
  if (lane == 0) {
    slot = atomicAdd(&cursors[e], 1);
    tslot[t * 2 + k] = slot;
  }
  slot = __shfl(slot, 0);
  const float4* xr = (const float4*)(x + (size_t)t * DIM);
  ushort4* dst = (ushort4*)(Xg + (size_t)slot * DIM);
#pragma unroll
  for (int i = 0; i < 4; ++i) {
    int idx = i * 64 + lane;
    float4 v = xr[idx];
    ushort4 o;
    o.x = f2b(v.x); o.y = f2b(v.y); o.z = f2b(v.z); o.w = f2b(v.w);
    dst[idx] = o;
  }
}

// ---------------- streaming fp32 -> bf16 convert (no transpose; coalesced) ----------------
__global__ void convert_bf16(const float* __restrict__ src, unsigned short* __restrict__ dst,
                             int n8) {
  int stride = gridDim.x * blockDim.x;
  for (int i = blockIdx.x * blockDim.x + threadIdx.x; i < n8; i += stride) {
    float4 v0 = ((const float4*)src)[i * 2];
    float4 v1 = ((const float4*)src)[i * 2 + 1];
    us8 o;
    o[0] = f2b(v0.x); o[1] = f2b(v0.y); o[2] = f2b(v0.z); o[3] = f2b(v0.w);
    o[4] = f2b(v1.x); o[5] = f2b(v1.y); o[6] = f2b(v1.z); o[7] = f2b(v1.w);
    ((us8*)dst)[i] = o;
  }
}

// ---------------- 128x128 grouped GEMM: A K-major (ds_read_b128 + XOR swz),
//                  B K-MAJOR source via tr_read subtiled LDS (no weight transpose) --------
// A: [slots][KTOT] bf16. Bsrc: [E][KTOT][NN] bf16 (k rows, n cols -- natural weight layout).
// B LDS layout (derived from m162 tr_read lane formula): 16 regions of 512 shorts,
// region(jn,kk)=jn+kk*8; within: off(n,k) = (n%16) + (k%4)*16 + ((k/8)%4)*64 + ((k%8)/4)*256.
// Stage: chunk c = wi*64 + l  ->  (kk=wi>>3, jn=wi&7, h2=l>>5, g=(l>>3)&3, h01=(l>>1)&3, n8=l&1),
//        k = kk*32 + g*8 + h2*4 + h01, n = jn*16 + n8*8  (global 16B chunk, n-contiguous).
// Read: ds_read_b64_tr_b16 pair at region base + l*8 (offsets 0 / 512B) -> lane gets
//        (n = jn*16 + (l&15), k = kk*32 + (l>>4)*8 + 0..7).
template <bool GELU, int KTOT, int NN, bool PARTIAL, bool SPLITK, int SPAN, int NCH>
__global__ __launch_bounds__(256, 4) void ffn_gemm128(
    const unsigned short* __restrict__ A, const unsigned short* __restrict__ Bsrc,
    const float* __restrict__ bias, void* __restrict__ OutP,
    const int* __restrict__ offsets, const int* __restrict__ ntiles_p,
    const int* __restrict__ tlist) {
  int gx = gridDim.x;
  int orig = blockIdx.y * gx + blockIdx.x;
  // grouped-aware XCD mapping: XCD x owns CONTIGUOUS tlist entries [9x, 9x+9)
  // (same expert runs), iterating n in NCH chunks x its 9 m-slots.
  int xcd   = orig & 7;
  int local = orig >> 3;               // [0, gx*9)
  int nc  = local / (NCH * 9);
  int rem = local - nc * (NCH * 9);
  int m   = rem / NCH;
  int nn  = rem - m * NCH;
  int xb  = nc * NCH + nn;
  int yb  = xcd * 9 + m;

  int kh = 0;
  if (SPLITK) { kh = xb & 1; xb >>= 1; }

  int ntiles = *ntiles_p;
  if (yb >= ntiles) return;
  int ent = tlist[yb];
  int e = ent >> 8, mt = ent & 255;
  int off = offsets[e];
  int n_e = offsets[e + 1] - off;
  int row0 = off + mt * 128;
  if (mt * 128 >= n_e) return;
  int rows_valid = n_e - mt * 128; if (rows_valid > 128) rows_valid = 128;
  int n0 = xb * 128;
  int kbase = kh * SPAN;

  __shared__ unsigned short As[128 * 64];
  __shared__ unsigned short Bs[64 * 128];

  int tid = threadIdx.x, w = tid >> 6, l = tid & 63;
  int wm = w >> 1, wn = w & 1;

  f32x4 acc[4][4] = {};

  const unsigned short* Ab = A + (size_t)row0 * KTOT;
  const unsigned short* Bg = Bsrc + (size_t)e * KTOT * NN + n0;
  int srow = l >> 3;                     // A: row within 8-row group
  int scol = ((l & 7) ^ (l >> 3)) * 8;   // A: pre-swizzled source chunk (shorts)
  // B staging decomposition (per-lane constants)
  int h2 = l >> 5, gS = (l >> 3) & 3, h01 = (l >> 1) & 3, n8 = l & 1;
  int kin = gS * 8 + h2 * 4 + h01;
  int nin = n8 * 8;

  unsigned bsOff = (unsigned)(uintptr_t)(__attribute__((address_space(3))) unsigned short*)Bs;
  unsigned vb = bsOff + (unsigned)l * 8 + (unsigned)wn * 4096;

#pragma unroll 1
  for (int k0 = kbase; k0 < kbase + SPAN; k0 += 64) {
#pragma unroll
    for (int i = 0; i < 4; ++i) {
      int R = w * 32 + i * 8;
      gload_lds16(Ab + (size_t)(R + srow) * KTOT + k0 + scol, &As[R * 64]);
      int wi = w * 4 + i;
      int kl = (wi >> 3) * 32 + kin;
      int nl = (wi & 7) * 16 + nin;
      gload_lds16(Bg + (size_t)(k0 + kl) * NN + nl, &Bs[wi * 512]);
    }
    __syncthreads();   // vmcnt(0) drain; resident blocks overlap each other
#pragma unroll
    for (int kk = 0; kk < 2; ++kk) {
      short4v lov[4], hiv[4];
#pragma unroll
      for (int j = 0; j < 4; ++j) {
        unsigned a = vb + (unsigned)(kk * 8192 + j * 1024);
        asm volatile("ds_read_b64_tr_b16 %0, %2 offset:0\n\t"
                     "ds_read_b64_tr_b16 %1, %2 offset:512"
                     : "=&v"(lov[j]), "=&v"(hiv[j]) : "v"(a));
      }
      int cb = (kk * 64 + (l >> 4) * 16) ^ ((l & 7) << 4);
      bf16x8 af[4];
#pragma unroll
      for (int i = 0; i < 4; ++i) {
        int row = wm * 64 + i * 16 + (l & 15);
        af[i] = *(const bf16x8*)((const char*)&As[0] + row * 128 + cb);
      }
      asm volatile("s_waitcnt lgkmcnt(0)" ::: "memory");
      __builtin_amdgcn_sched_barrier(0);
#pragma unroll
      for (int j = 0; j < 4; ++j) {
        bf16x8 bfr = __builtin_bit_cast(
            bf16x8, (short8v)__builtin_shufflevector(lov[j], hiv[j], 0, 1, 2, 3, 4, 5, 6, 7));
#pragma unroll
        for (int i = 0; i < 4; ++i)
          acc[i][j] = __builtin_amdgcn_mfma_f32_16x16x32_bf16(af[i], bfr, acc[i][j], 0, 0, 0);
      }
    }
    __syncthreads();
  }

  int cr = (l >> 4) * 4, cc = l & 15;
#pragma unroll
  for (int i = 0; i < 4; ++i) {
#pragma unroll
    for (int r = 0; r < 4; ++r) {
      int rl = wm * 64 + i * 16 + cr + r;
      if (rl < rows_valid) {
#pragma unroll
        for (int j = 0; j < 4; ++j) {
          int col = n0 + wn * 64 + j * 16 + cc;
          if (PARTIAL) {
            unsigned short* Oh = (unsigned short*)OutP;   // bf16 K-half partial, bias deferred
            Oh[((size_t)(kh * PADROWS) + row0 + rl) * NN + col] = f2b(acc[i][j][r]);
          } else {
            unsigned short* Oh = (unsigned short*)OutP;
            float v = acc[i][j][r] + bias[(size_t)e * NN + col];
            if (GELU) v = 0.5f * v * (1.0f + erff(v * 0.70710678118654752f));
            Oh[(size_t)(row0 + rl) * NN + col] = f2b(v);
          }
        }
      }
    }
  }
}

// ---------------- combine: out = x + sum_k w_k*(EOp0[s_k]+EOp1[s_k]+b2[e_k]) ----------------
__global__ void combine_kernel(const float* __restrict__ x, const unsigned short* __restrict__ EOp,
                               const int* __restrict__ tslot, const int* __restrict__ tidx,
                               const float* __restrict__ tw, const float* __restrict__ b2,
                               float* __restrict__ out) {
  int t = blockIdx.x;
  int s0 = tslot[t * 2], s1 = tslot[t * 2 + 1];
  int e0 = tidx[t * 2], e1 = tidx[t * 2 + 1];
  float w0 = tw[t * 2], w1 = tw[t * 2 + 1];
  int i = threadIdx.x;
  float4 xv = ((const float4*)(x + (size_t)t * DIM))[i];
  ushort4 a0 = ((const ushort4*)(EOp + (size_t)s0 * DIM))[i];
  ushort4 a1 = ((const ushort4*)(EOp + ((size_t)PADROWS + s0) * DIM))[i];
  ushort4 c0 = ((const ushort4*)(EOp + (size_t)s1 * DIM))[i];
  ushort4 c1 = ((const ushort4*)(EOp + ((size_t)PADROWS + s1) * DIM))[i];
  float4 b0 = ((const float4*)(b2 + (size_t)e0 * DIM))[i];
  float4 b1 = ((const float4*)(b2 + (size_t)e1 * DIM))[i];
  float4 o;
  o.x = xv.x + w0 * (b2f(a0.x) + b2f(a1.x) + b0.x) + w1 * (b2f(c0.x) + b2f(c1.x) + b1.x);
  o.y = xv.y + w0 * (b2f(a0.y) + b2f(a1.y) + b0.y) + w1 * (b2f(c0.y) + b2f(c1.y) + b1.y);
  o.z = xv.z + w0 * (b2f(a0.z) + b2f(a1.z) + b0.z) + w1 * (b2f(c0.z) + b2f(c1.z) + b1.z);
  o.w = xv.w + w0 * (b2f(a0.w) + b2f(a1.w) + b0.w) + w1 * (b2f(c0.w) + b2f(c1.w) + b1.w);
  ((float4*)(out + (size_t)t * DIM))[i] = o;
}

extern "C" void kernel_launch(void* const* d_in, const int* in_sizes, int n_in,
                              void* d_out, int out_size, void* d_ws, size_t ws_size,
                              hipStream_t stream) {
  const float* x        = (const float*)d_in[0];
  const float* router_w = (const float*)d_in[1];
  const float* router_b = (const float*)d_in[2];
  const float* w1       = (const float*)d_in[3];
  const float* b1       = (const float*)d_in[4];
  const float* w2       = (const float*)d_in[5];
  const float* b2       = (const float*)d_in[6];
  float* out = (float*)d_out;
  char* ws = (char*)d_ws;

  int*   counts  = (int*)(ws + 0);
  int*   cursors = (int*)(ws + 64);
  int*   offsets = (int*)(ws + 128);
  int*   ntilesp = (int*)(ws + 192);
  int*   tlist   = (int*)(ws + 256);
  int*   tidx    = (int*)(ws + 4096);
  float* tw      = (float*)(ws + 36864);
  int*   tslot   = (int*)(ws + 69632);
  // big buffers: [Xg 17.3][H 69.2][W1c 67.1 | EOp(bf16, 34.6, aliases W1c after GEMM1)][W2c 67.1]
  const size_t XG_OFF  = 1u << 20;
  const size_t XG_B    = (size_t)PADROWS * DIM * 2;
  const size_t H_OFF   = XG_OFF + XG_B;
  const size_t H_B     = (size_t)PADROWS * FDIM * 2;
  const size_t W1C_OFF = H_OFF + H_B;
  const size_t WC_B    = (size_t)NEXP * DIM * FDIM * 2;    // 67.1 MB
  const size_t W2C_OFF = W1C_OFF + WC_B;
  const size_t EOP_OFF = W1C_OFF;                          // alias: W1c dead after GEMM1
  unsigned short* Xg  = (unsigned short*)(ws + XG_OFF);
  unsigned short* H   = (unsigned short*)(ws + H_OFF);
  unsigned short* W1c = (unsigned short*)(ws + W1C_OFF);
  unsigned short* W2c = (unsigned short*)(ws + W2C_OFF);
  unsigned short* EOp = (unsigned short*)(ws + EOP_OFF);   // [2][PADROWS][DIM] bf16

  hipMemsetAsync(ws, 0, 512, stream);
  // weights: streaming fp32 -> bf16, K-major layout preserved (no transpose)
  convert_bf16<<<2048, 256, 0, stream>>>(w1, W1c, NEXP * DIM * FDIM / 8);
  convert_bf16<<<2048, 256, 0, stream>>>(w2, W2c, NEXP * DIM * FDIM / 8);
  router_kernel<<<T_TOKENS / 4, 256, 0, stream>>>(x, router_w, router_b, tidx, tw, counts);
  scan_kernel<<<1, 64, 0, stream>>>(counts, offsets, cursors, ntilesp, tlist);
  gather_kernel<<<NASSIGN / 4, 256, 0, stream>>>(x, tidx, cursors, tslot, Xg);
  // H = gelu(Xg @ W1 + b1): W1c [E][1024][4096] consumed K-major via tr_read
  ffn_gemm128<true, DIM, FDIM, false, false, DIM, 8><<<dim3(FDIM / 128, 72), 256, 0, stream>>>(
      Xg, W1c, b1, (void*)H, offsets, ntilesp, tlist);
  // EOp[kh] = H @ W2 (K halves, bf16 partials, bias deferred): W2c [E][4096][1024]
  ffn_gemm128<false, FDIM, DIM, true, true, FDIM / 2, 4><<<dim3(DIM / 128 * 2, 72), 256, 0, stream>>>(
      H, W2c, b2, (void*)EOp, offsets, ntilesp, tlist);
  combine_kernel<<<T_TOKENS, 256, 0, stream>>>(x, EOp, tslot, tidx, tw, b2, out);
}

// Round 10
// 519.890 us; speedup vs baseline: 1.1160x; 1.1160x over previous
//
#include <hip/hip_runtime.h>

#define T_TOKENS 4096   // B*S
#define DIM      1024   // D
#define NEXP     8      // E
#define FDIM     4096   // F
#define NASSIGN  8192   // T_TOKENS * K
#define PADROWS  8448

typedef __bf16 bf16x8 __attribute__((ext_vector_type(8)));
typedef float  f32x4  __attribute__((ext_vector_type(4)));

__device__ __forceinline__ unsigned short f2b(float f) {
  unsigned u = __builtin_bit_cast(unsigned, f);
  u = u + 0x7fffu + ((u >> 16) & 1u);   // RNE, finite inputs only
  return (unsigned short)(u >> 16);
}
__device__ __forceinline__ unsigned short cvt_bf16(float f) {
  return __builtin_bit_cast(unsigned short, (__bf16)f);   // v_cvt_pk_bf16_f32 (RNE)
}
__device__ __forceinline__ float b2f(unsigned short h) {
  unsigned u = ((unsigned)h) << 16;
  return __builtin_bit_cast(float, u);
}
__device__ __forceinline__ void gload_lds16(const void* g, void* l) {
  __builtin_amdgcn_global_load_lds(
      (const __attribute__((address_space(1))) void*)g,
      (__attribute__((address_space(3))) void*)l, 16, 0, 0);
}

// ---------------- router ----------------
__global__ void router_kernel(const float* __restrict__ x, const float* __restrict__ rw,
                              const float* __restrict__ rb, int* __restrict__ tidx,
                              float* __restrict__ tw, int* __restrict__ counts) {
  int gid = blockIdx.x * blockDim.x + threadIdx.x;
  int t = gid >> 6;
  int lane = threadIdx.x & 63;
  if (t >= T_TOKENS) return;
  const float* xr = x + (size_t)t * DIM;
  float acc[NEXP];
#pragma unroll
  for (int e = 0; e < NEXP; ++e) acc[e] = 0.f;
  for (int d = lane; d < DIM; d += 64) {
    float xv = xr[d];
    const float* r = rw + (size_t)d * NEXP;
#pragma unroll
    for (int e = 0; e < NEXP; ++e) acc[e] += xv * r[e];
  }
#pragma unroll
  for (int e = 0; e < NEXP; ++e) {
#pragma unroll
    for (int off = 32; off > 0; off >>= 1) acc[e] += __shfl_xor(acc[e], off);
  }
  if (lane == 0) {
    float lg[NEXP], m = -1e30f;
#pragma unroll
    for (int e = 0; e < NEXP; ++e) { lg[e] = acc[e] + rb[e]; m = fmaxf(m, lg[e]); }
    float p[NEXP], Z = 0.f;
#pragma unroll
    for (int e = 0; e < NEXP; ++e) { p[e] = expf(lg[e] - m); Z += p[e]; }
    int i0 = 0;
#pragma unroll
    for (int e = 1; e < NEXP; ++e) if (p[e] > p[i0]) i0 = e;
    int i1 = (i0 == 0) ? 1 : 0;
#pragma unroll
    for (int e = 0; e < NEXP; ++e) if (e != i0 && p[e] > p[i1]) i1 = e;
    float q0 = p[i0] / Z, q1 = p[i1] / Z;
    float s = q0 + q1 + 1e-8f;
    tidx[t * 2] = i0; tidx[t * 2 + 1] = i1;
    tw[t * 2] = q0 / s; tw[t * 2 + 1] = q1 / s;
    atomicAdd(&counts[i0], 1); atomicAdd(&counts[i1], 1);
  }
}

// ---------------- scan: offsets, cursors, 128-row tile list ----------------
__global__ void scan_kernel(const int* __restrict__ counts, int* __restrict__ offsets,
                            int* __restrict__ cursors, int* __restrict__ ntiles_p,
                            int* __restrict__ tlist) {
  if (threadIdx.x == 0) {
    int s = 0;
    for (int e = 0; e < NEXP; ++e) { offsets[e] = s; cursors[e] = s; s += counts[e]; }
    offsets[NEXP] = s;
    int nt = 0;
    for (int e = 0; e < NEXP; ++e) {
      int ne = counts[e];
      int mts = (ne + 127) >> 7;
      for (int mt = 0; mt < mts; ++mt) tlist[nt++] = (e << 8) | mt;
    }
    *ntiles_p = nt;   // <= 71
  }
}

// ---------------- gather x rows (fp32 -> bf16) ----------------
__global__ void gather_kernel(const float* __restrict__ x, const int* __restrict__ tidx,
                              int* __restrict__ cursors, int* __restrict__ tslot,
                              unsigned short* __restrict__ Xg) {
  int aid = (blockIdx.x * blockDim.x + threadIdx.x) >> 6;
  int lane = threadIdx.x & 63;
  if (aid >= NASSIGN) return;
  int t = aid >> 1, k = aid & 1;
  int e = tidx[t * 2 + k];
  int slot = 0;
  if (lane == 0) {
    slot = atomicAdd(&cursors[e], 1);
    tslot[t * 2 + k] = slot;
  }
  slot = __shfl(slot, 0);
  const float4* xr = (const float4*)(x + (size_t)t * DIM);
  ushort4* dst = (ushort4*)(Xg + (size_t)slot * DIM);
#pragma unroll
  for (int i = 0; i < 4; ++i) {
    int idx = i * 64 + lane;
    float4 v = xr[idx];
    ushort4 o;
    o.x = cvt_bf16(v.x); o.y = cvt_bf16(v.y); o.z = cvt_bf16(v.z); o.w = cvt_bf16(v.w);
    dst[idx] = o;
  }
}

// ---------------- fused transpose+convert for BOTH weights (one launch) ----------------
// z = e + 8*which: which=0: w1 [D][F] -> W1T [F][D]; which=1: w2 [F][D] -> W2T [F*? ->..]
// Body: src [R][C] f32 -> dst [C][R] bf16, 64x64 tiles, LDS stride 66 (conflict-light).
__global__ void transpose_cvt_both(const float* __restrict__ w1, const float* __restrict__ w2,
                                   unsigned short* __restrict__ W1T,
                                   unsigned short* __restrict__ W2T) {
  __shared__ unsigned short tile[64][66];
  int z = blockIdx.z;
  int e = z & 7, which = z >> 3;
  int R = which ? FDIM : DIM;
  int C = which ? DIM : FDIM;
  const float* s = (which ? w2 : w1) + (size_t)e * DIM * FDIM;
  unsigned short* d = (which ? W2T : W1T) + (size_t)e * DIM * FDIM;
  int c0 = (which ? (int)blockIdx.y : (int)blockIdx.x) * 64;   // C index: <16 or <64
  int r0 = (which ? (int)blockIdx.x : (int)blockIdx.y) * 64;   // R index: <64 or <16
  int tx = threadIdx.x & 15, ty = threadIdx.x >> 4;   // ty 0..15
#pragma unroll
  for (int i = 0; i < 4; ++i) {
    int r = i * 16 + ty;
    float4 v = *(const float4*)(s + (size_t)(r0 + r) * C + c0 + tx * 4);
    ushort2 lo, hi;
    lo.x = cvt_bf16(v.x); lo.y = cvt_bf16(v.y); hi.x = cvt_bf16(v.z); hi.y = cvt_bf16(v.w);
    *(ushort2*)&tile[r][tx * 4]     = lo;
    *(ushort2*)&tile[r][tx * 4 + 2] = hi;
  }
  __syncthreads();
#pragma unroll
  for (int i = 0; i < 4; ++i) {
    int c = i * 16 + ty;
    ushort4 o;
    o.x = tile[tx * 4 + 0][c];
    o.y = tile[tx * 4 + 1][c];
    o.z = tile[tx * 4 + 2][c];
    o.w = tile[tx * 4 + 3][c];
    *(ushort4*)(d + (size_t)(c0 + c) * R + r0 + tx * 4) = o;
  }
}

// ---------------- 128x128 grouped GEMM: R8 core + grouped XCD supertile mapping ----------
// A: [slots][AS] bf16, B: [E][N][AS] bf16 (N-major). 4 waves (2M x 2N), per-wave C 64x64.
// __launch_bounds__(256,4): 128 reg/wave = 64 VGPR + 64 AGPR acc. (256,5) spills -- keep 4.
// Mapping: XCD x owns CONTIGUOUS tlist entries [9x, 9x+9) (same-expert m-tile runs);
// iterates n in NCH chunks so the B-chunk stays L2-resident across its 9 m-slots.
template <bool GELU, int AS, bool PARTIAL, bool SPLITK, int SPAN, int NCH>
__global__ __launch_bounds__(256, 4) void ffn_gemm128(
    const unsigned short* __restrict__ A, const unsigned short* __restrict__ Bw,
    const float* __restrict__ bias, void* __restrict__ OutP,
    const int* __restrict__ offsets, const int* __restrict__ ntiles_p,
    const int* __restrict__ tlist, int N) {
  int gx = gridDim.x;
  int orig = blockIdx.y * gx + blockIdx.x;
  int xcd   = orig & 7;
  int local = orig >> 3;               // [0, gx*9)
  int nc  = local / (NCH * 9);
  int rem = local - nc * (NCH * 9);
  int m   = rem / NCH;
  int nn  = rem - m * NCH;
  int xb  = nc * NCH + nn;
  int yb  = xcd * 9 + m;

  int kh = 0;
  if (SPLITK) { kh = xb & 1; xb >>= 1; }

  int ntiles = *ntiles_p;
  if (yb >= ntiles) return;
  int ent = tlist[yb];
  int e = ent >> 8, mt = ent & 255;
  int off = offsets[e];
  int n_e = offsets[e + 1] - off;
  int row0 = off + mt * 128;
  if (mt * 128 >= n_e) return;
  int rows_valid = n_e - mt * 128; if (rows_valid > 128) rows_valid = 128;
  int n0 = xb * 128;
  int kbase = kh * SPAN;

  __shared__ unsigned short As[128 * 64];
  __shared__ unsigned short Bs[128 * 64];

  int tid = threadIdx.x, w = tid >> 6, l = tid & 63;
  int wm = w >> 1, wn = w & 1;

  f32x4 acc[4][4] = {};

  const unsigned short* Ab = A + (size_t)row0 * AS;
  const unsigned short* Bb = Bw + ((size_t)e * N + n0) * AS;
  int srow = l >> 3;                     // row within 8-row group
  int scol = ((l & 7) ^ (l >> 3)) * 8;   // pre-swizzled source chunk (shorts)

#pragma unroll 1
  for (int k0 = kbase; k0 < kbase + SPAN; k0 += 64) {
#pragma unroll
    for (int i = 0; i < 4; ++i) {
      int R = w * 32 + i * 8;
      gload_lds16(Ab + (size_t)(R + srow) * AS + k0 + scol, &As[R * 64]);
      gload_lds16(Bb + (size_t)(R + srow) * AS + k0 + scol, &Bs[R * 64]);
    }
    __syncthreads();   // vmcnt(0) drain; resident blocks overlap each other
#pragma unroll
    for (int kk = 0; kk < 2; ++kk) {
      int cb = (kk * 64 + (l >> 4) * 16) ^ ((l & 7) << 4);   // swizzled col byte
      bf16x8 af[4], bfr[4];
#pragma unroll
      for (int i = 0; i < 4; ++i) {
        int row = wm * 64 + i * 16 + (l & 15);
        af[i] = *(const bf16x8*)((const char*)&As[0] + row * 128 + cb);
      }
#pragma unroll
      for (int j = 0; j < 4; ++j) {
        int row = wn * 64 + j * 16 + (l & 15);
        bfr[j] = *(const bf16x8*)((const char*)&Bs[0] + row * 128 + cb);
      }
#pragma unroll
      for (int i = 0; i < 4; ++i)
#pragma unroll
        for (int j = 0; j < 4; ++j)
          acc[i][j] = __builtin_amdgcn_mfma_f32_16x16x32_bf16(af[i], bfr[j], acc[i][j], 0, 0, 0);
    }
    __syncthreads();
  }

  int cr = (l >> 4) * 4, cc = l & 15;
#pragma unroll
  for (int i = 0; i < 4; ++i) {
#pragma unroll
    for (int r = 0; r < 4; ++r) {
      int rl = wm * 64 + i * 16 + cr + r;
      if (rl < rows_valid) {
#pragma unroll
        for (int j = 0; j < 4; ++j) {
          int col = n0 + wn * 64 + j * 16 + cc;
          unsigned short* Oh = (unsigned short*)OutP;
          if (PARTIAL) {
            Oh[((size_t)(kh * PADROWS) + row0 + rl) * N + col] = cvt_bf16(acc[i][j][r]);
          } else {
            float v = acc[i][j][r] + bias[(size_t)e * N + col];
            if (GELU) v = 0.5f * v * (1.0f + erff(v * 0.70710678118654752f));
            Oh[(size_t)(row0 + rl) * N + col] = cvt_bf16(v);
          }
        }
      }
    }
  }
}

// ---------------- combine: out = x + sum_k w_k*(EOp0[s_k]+EOp1[s_k]+b2[e_k]) ----------------
__global__ void combine_kernel(const float* __restrict__ x, const unsigned short* __restrict__ EOp,
                               const int* __restrict__ tslot, const int* __restrict__ tidx,
                               const float* __restrict__ tw, const float* __restrict__ b2,
                               float* __restrict__ out) {
  int t = blockIdx.x;
  int s0 = tslot[t * 2], s1 = tslot[t * 2 + 1];
  int e0 = tidx[t * 2], e1 = tidx[t * 2 + 1];
  float w0 = tw[t * 2], w1 = tw[t * 2 + 1];
  int i = threadIdx.x;
  float4 xv = ((const float4*)(x + (size_t)t * DIM))[i];
  ushort4 a0 = ((const ushort4*)(EOp + (size_t)s0 * DIM))[i];
  ushort4 a1 = ((const ushort4*)(EOp + ((size_t)PADROWS + s0) * DIM))[i];
  ushort4 c0 = ((const ushort4*)(EOp + (size_t)s1 * DIM))[i];
  ushort4 c1 = ((const ushort4*)(EOp + ((size_t)PADROWS + s1) * DIM))[i];
  float4 b0 = ((const float4*)(b2 + (size_t)e0 * DIM))[i];
  float4 b1 = ((const float4*)(b2 + (size_t)e1 * DIM))[i];
  float4 o;
  o.x = xv.x + w0 * (b2f(a0.x) + b2f(a1.x) + b0.x) + w1 * (b2f(c0.x) + b2f(c1.x) + b1.x);
  o.y = xv.y + w0 * (b2f(a0.y) + b2f(a1.y) + b0.y) + w1 * (b2f(c0.y) + b2f(c1.y) + b1.y);
  o.z = xv.z + w0 * (b2f(a0.z) + b2f(a1.z) + b0.z) + w1 * (b2f(c0.z) + b2f(c1.z) + b1.z);
  o.w = xv.w + w0 * (b2f(a0.w) + b2f(a1.w) + b0.w) + w1 * (b2f(c0.w) + b2f(c1.w) + b1.w);
  ((float4*)(out + (size_t)t * DIM))[i] = o;
}

extern "C" void kernel_launch(void* const* d_in, const int* in_sizes, int n_in,
                              void* d_out, int out_size, void* d_ws, size_t ws_size,
                              hipStream_t stream) {
  const float* x        = (const float*)d_in[0];
  const float* router_w = (const float*)d_in[1];
  const float* router_b = (const float*)d_in[2];
  const float* w1       = (const float*)d_in[3];
  const float* b1       = (const float*)d_in[4];
  const float* w2       = (const float*)d_in[5];
  const float* b2       = (const float*)d_in[6];
  float* out = (float*)d_out;
  char* ws = (char*)d_ws;

  int*   counts  = (int*)(ws + 0);
  int*   cursors = (int*)(ws + 64);
  int*   offsets = (int*)(ws + 128);
  int*   ntilesp = (int*)(ws + 192);
  int*   tlist   = (int*)(ws + 256);
  int*   tidx    = (int*)(ws + 4096);
  float* tw      = (float*)(ws + 36864);
  int*   tslot   = (int*)(ws + 69632);
  const size_t XG_OFF  = 1u << 20;
  const size_t XG_B    = (size_t)PADROWS * DIM * 2;
  const size_t H_OFF   = XG_OFF + XG_B;
  const size_t H_B     = (size_t)PADROWS * FDIM * 2;
  const size_t W2T_OFF = H_OFF + H_B;
  const size_t WT_B    = (size_t)NEXP * DIM * FDIM * 2;
  const size_t W1T_OFF = W2T_OFF + WT_B;
  const size_t EOP_OFF = W1T_OFF;                          // alias (W1T dead after GEMM1)
  unsigned short* Xg  = (unsigned short*)(ws + XG_OFF);
  unsigned short* H   = (unsigned short*)(ws + H_OFF);
  unsigned short* W2T = (unsigned short*)(ws + W2T_OFF);
  unsigned short* W1T = (unsigned short*)(ws + W1T_OFF);
  unsigned short* EOp = (unsigned short*)(ws + EOP_OFF);   // [2][PADROWS][DIM] bf16

  hipMemsetAsync(ws, 0, 512, stream);
  router_kernel<<<T_TOKENS / 4, 256, 0, stream>>>(x, router_w, router_b, tidx, tw, counts);
  scan_kernel<<<1, 64, 0, stream>>>(counts, offsets, cursors, ntilesp, tlist);
  gather_kernel<<<NASSIGN / 4, 256, 0, stream>>>(x, tidx, cursors, tslot, Xg);
  // both weight transposes in one launch: z = e + 8*which
  transpose_cvt_both<<<dim3(64, 16, 16), 256, 0, stream>>>(w1, w2, W1T, W2T);
  // H = gelu(Xg @ W1 + b1): x = 32 n-tiles, y = 72; NCH=8 -> 2MB L2-resident B-chunks
  ffn_gemm128<true, DIM, false, false, DIM, 8><<<dim3(FDIM / 128, 72), 256, 0, stream>>>(
      Xg, W1T, b1, (void*)H, offsets, ntilesp, tlist, FDIM);
  // EOp[kh] = H @ W2 (K halves, bf16 partials, bias deferred): x = 8 n-tiles x 2 kh; NCH=4
  ffn_gemm128<false, FDIM, true, true, FDIM / 2, 4><<<dim3(DIM / 128 * 2, 72), 256, 0, stream>>>(
      H, W2T, b2, (void*)EOp, offsets, ntilesp, tlist, DIM);
  combine_kernel<<<T_TOKENS, 256, 0, stream>>>(x, EOp, tslot, tidx, tw, b2, out);
}